// Round 18
// baseline (130.896 us; speedup 1.0000x reference)
//
#include <hip/hip_runtime.h>
#include <hip/hip_bf16.h>

typedef __bf16 bf16;
typedef __attribute__((ext_vector_type(8))) __bf16 bf16x8;
typedef __attribute__((ext_vector_type(4))) __bf16 bf16x4;
typedef __attribute__((ext_vector_type(4))) float f32x4;

// ===========================================================================
// fp32 -> bf16 conversion pass (7 segments in one launch)
// ===========================================================================
struct CvtArgs {
  const float* src[7];
  bf16* dst[7];
  int n4[7];  // element count / 4
};

__global__ __launch_bounds__(256) void cvt_kernel(CvtArgs a) {
  const int seg = blockIdx.y;
  const float4* s = (const float4*)a.src[seg];
  bf16x4* d = (bf16x4*)a.dst[seg];
  const int n = a.n4[seg];
  const int stride = gridDim.x * 256;
  for (int i = blockIdx.x * 256 + threadIdx.x; i < n; i += stride) {
    const float4 v = s[i];
    bf16x4 h;
    h[0] = (bf16)v.x; h[1] = (bf16)v.y; h[2] = (bf16)v.z; h[3] = (bf16)v.w;
    d[i] = h;
  }
}

// ===========================================================================
// gload16: async global->LDS 16B per lane
// ===========================================================================
__device__ __forceinline__ void gload16(const void* g, void* l) {
  __builtin_amdgcn_global_load_lds(
      (const __attribute__((address_space(1))) void*)g,
      (__attribute__((address_space(3))) void*)l, 16, 0, 0);
}

// ===========================================================================
// bf16 GEMM, counted-vmcnt triple-buffered pipeline, 128x128 tile (qkv).
// ===========================================================================
__device__ __forceinline__ void gemm_core2(const bf16* __restrict__ A,
                                           const bf16* __restrict__ W,
                                           const float* __restrict__ bias,
                                           void* __restrict__ C,
                                           float scale, int mode,
                                           int bx, int by) {
  constexpr int K = 1024, N = 1024, BK = 32, NT = K / BK;
  __shared__ __align__(16) bf16 As[3][128 * BK];
  __shared__ __align__(16) bf16 Bs[3][128 * BK];

  const int tid = threadIdx.x;
  const int lane = tid & 63;
  const int w = tid >> 6;
  const int wm = w >> 1, wn = w & 1;
  const int g = lane >> 4, c16 = lane & 15;
  const int row0 = by * 128;
  const int col0 = bx * 128;

  const int sr = tid >> 2;
  const int ssw = ((tid & 3) ^ (sr & 3)) * 8;
  const int sdst = tid * 8;

  const int aoff = (wm * 64 + c16) * BK + ((g ^ (c16 & 3)) * 8);
  const int boff = (wn * 64 + c16) * BK + ((g ^ (c16 & 3)) * 8);

  f32x4 acc[4][4] = {};

#define STAGE2(buf, kt)                                                          \
  {                                                                              \
    const int k0_ = (kt)*BK;                                                     \
    gload16(&A[(size_t)(row0 + sr) * K + k0_ + ssw], &As[buf][sdst]);            \
    gload16(&A[(size_t)(row0 + 64 + sr) * K + k0_ + ssw], &As[buf][2048 + sdst]);\
    gload16(&W[(size_t)(col0 + sr) * K + k0_ + ssw], &Bs[buf][sdst]);            \
    gload16(&W[(size_t)(col0 + 64 + sr) * K + k0_ + ssw], &Bs[buf][2048 + sdst]);\
  }

  STAGE2(0, 0);
  STAGE2(1, 1);

#pragma unroll 1
  for (int kt = 0; kt < NT; ++kt) {
    const int cur = kt % 3;
    if (kt == NT - 1)
      asm volatile("s_waitcnt vmcnt(0)" ::: "memory");
    else
      asm volatile("s_waitcnt vmcnt(4)" ::: "memory");
    __builtin_amdgcn_s_barrier();
    __builtin_amdgcn_sched_barrier(0);

    if (kt + 2 < NT) {
      const int nb = (cur + 2 >= 3) ? cur - 1 : cur + 2;
      STAGE2(nb, kt + 2);
    }

    bf16x8 a[4], b[4];
#pragma unroll
    for (int m = 0; m < 4; ++m) a[m] = *(const bf16x8*)&As[cur][aoff + m * 512];
#pragma unroll
    for (int n = 0; n < 4; ++n) b[n] = *(const bf16x8*)&Bs[cur][boff + n * 512];

    __builtin_amdgcn_s_setprio(1);
#pragma unroll
    for (int m = 0; m < 4; ++m)
#pragma unroll
      for (int n = 0; n < 4; ++n)
        acc[m][n] = __builtin_amdgcn_mfma_f32_16x16x32_bf16(a[m], b[n], acc[m][n], 0, 0, 0);
    __builtin_amdgcn_s_setprio(0);
  }
#undef STAGE2

#pragma unroll
  for (int m = 0; m < 4; ++m) {
#pragma unroll
    for (int n = 0; n < 4; ++n) {
      const int col = col0 + wn * 64 + n * 16 + c16;
      if (mode == 2) {
        const int row = row0 + wm * 64 + m * 16 + g * 4;
        const int bb = row >> 11, s = row & 2047;
        const int hh = col >> 6, j = col & 63;
        bf16x4 hv;
#pragma unroll
        for (int r = 0; r < 4; ++r)
          hv[r] = (bf16)((acc[m][n][r] + bias[col]) * scale);
        *(bf16x4*)&((bf16*)C)[(((size_t)bb * 16 + hh) * 64 + j) * 2048 + s] = hv;
      } else {
#pragma unroll
        for (int r = 0; r < 4; ++r) {
          const int row = row0 + wm * 64 + m * 16 + g * 4 + r;
          const float v = (acc[m][n][r] + bias[col]) * scale;
          if (mode == 1) {
            const int bb = row >> 11, s = row & 2047;
            const int hh = col >> 6, j = col & 63;
            ((bf16*)C)[(((size_t)bb * 16 + hh) * 2048 + s) * 64 + j] = (bf16)v;
          } else {
            ((float*)C)[(size_t)row * N + col] = v;
          }
        }
      }
    }
  }
}

// ===========================================================================
// bf16 GEMM, counted pipeline, 128x64 tile (o_gemm): 512 blocks, 2/CU.
// ===========================================================================
__device__ __forceinline__ void gemm_core3(const bf16* __restrict__ A,
                                           const bf16* __restrict__ W,
                                           const float* __restrict__ bias,
                                           float* __restrict__ C,
                                           int bx, int by) {
  constexpr int K = 1024, N = 1024, BK = 32, NT = K / BK;
  __shared__ __align__(16) bf16 As[3][128 * BK];
  __shared__ __align__(16) bf16 Bs[3][64 * BK];

  const int tid = threadIdx.x;
  const int lane = tid & 63;
  const int w = tid >> 6;
  const int wm = w >> 1, wn = w & 1;
  const int g = lane >> 4, c16 = lane & 15;
  const int row0 = by * 128;
  const int col0 = bx * 64;

  const int sr = tid >> 2;
  const int ssw = ((tid & 3) ^ (sr & 3)) * 8;
  const int sdst = tid * 8;

  const int aoff = (wm * 64 + c16) * BK + ((g ^ (c16 & 3)) * 8);
  const int boff = (wn * 32 + c16) * BK + ((g ^ (c16 & 3)) * 8);

  f32x4 acc[4][2] = {};

#define STAGE3(buf, kt)                                                          \
  {                                                                              \
    const int k0_ = (kt)*BK;                                                     \
    gload16(&A[(size_t)(row0 + sr) * K + k0_ + ssw], &As[buf][sdst]);            \
    gload16(&A[(size_t)(row0 + 64 + sr) * K + k0_ + ssw], &As[buf][2048 + sdst]);\
    gload16(&W[(size_t)(col0 + sr) * K + k0_ + ssw], &Bs[buf][sdst]);            \
  }

  STAGE3(0, 0);
  STAGE3(1, 1);

#pragma unroll 1
  for (int kt = 0; kt < NT; ++kt) {
    const int cur = kt % 3;
    if (kt == NT - 1)
      asm volatile("s_waitcnt vmcnt(0)" ::: "memory");
    else
      asm volatile("s_waitcnt vmcnt(3)" ::: "memory");
    __builtin_amdgcn_s_barrier();
    __builtin_amdgcn_sched_barrier(0);

    if (kt + 2 < NT) {
      const int nb = (cur + 2 >= 3) ? cur - 1 : cur + 2;
      STAGE3(nb, kt + 2);
    }

    bf16x8 a[4], b[2];
#pragma unroll
    for (int m = 0; m < 4; ++m) a[m] = *(const bf16x8*)&As[cur][aoff + m * 512];
#pragma unroll
    for (int n = 0; n < 2; ++n) b[n] = *(const bf16x8*)&Bs[cur][boff + n * 512];

    __builtin_amdgcn_s_setprio(1);
#pragma unroll
    for (int m = 0; m < 4; ++m)
#pragma unroll
      for (int n = 0; n < 2; ++n)
        acc[m][n] = __builtin_amdgcn_mfma_f32_16x16x32_bf16(a[m], b[n], acc[m][n], 0, 0, 0);
    __builtin_amdgcn_s_setprio(0);
  }
#undef STAGE3

#pragma unroll
  for (int m = 0; m < 4; ++m) {
#pragma unroll
    for (int n = 0; n < 2; ++n) {
      const int col = col0 + wn * 32 + n * 16 + c16;
#pragma unroll
      for (int r = 0; r < 4; ++r) {
        const int row = row0 + wm * 64 + m * 16 + g * 4 + r;
        C[(size_t)row * N + col] = acc[m][n][r] + bias[col];
      }
    }
  }
}

__device__ __forceinline__ void xcd_swz(int& bx, int& by, int& bz) {
  const int lid = ((int)blockIdx.z * 32 + (int)blockIdx.y) * 8 + (int)blockIdx.x;
  const int cpx = ((int)gridDim.z * 256) >> 3;
  int s = (lid & 7) * cpx + (lid >> 3);
  bx = s & 7;
  by = (s >> 3) & 31;
  bz = s >> 8;
}

__device__ __forceinline__ void xcd_swz2(int& bx, int& by) {
  const int gx = (int)gridDim.x;
  const int total = gx * (int)gridDim.y;
  const int lid = (int)blockIdx.y * gx + (int)blockIdx.x;
  const int cpx = total >> 3;
  const int s = (lid & 7) * cpx + (lid >> 3);
  bx = s & (gx - 1);
  by = s / gx;
}

__global__ __launch_bounds__(256, 3) void qkv_gemm_kernel(
    const bf16* __restrict__ qa, const bf16* __restrict__ ka, const bf16* __restrict__ va,
    const bf16* __restrict__ qw, const bf16* __restrict__ kw, const bf16* __restrict__ vw,
    const float* __restrict__ qb, const float* __restrict__ kb, const float* __restrict__ vb,
    bf16* __restrict__ Qo, bf16* __restrict__ Ko, bf16* __restrict__ Vo, float qscale) {
  int bx, by, bz;
  xcd_swz(bx, by, bz);
  const bf16* A = (bz == 0) ? qa : (bz == 1) ? ka : va;
  const bf16* W = (bz == 0) ? qw : (bz == 1) ? kw : vw;
  const float* bias = (bz == 0) ? qb : (bz == 1) ? kb : vb;
  bf16* C = (bz == 0) ? Qo : (bz == 1) ? Ko : Vo;
  const float scale = (bz == 0) ? qscale : 1.0f;
  const int mode = (bz == 2) ? 2 : 1;
  gemm_core2(A, W, bias, C, scale, mode, bx, by);
}

__global__ __launch_bounds__(256, 4) void o_gemm_kernel(
    const bf16* __restrict__ A, const bf16* __restrict__ W,
    const float* __restrict__ bias, float* __restrict__ C) {
  int bx, by;
  xcd_swz2(bx, by);
  gemm_core3(A, W, bias, C, bx, by);
}

// ===========================================================================
// Legacy fp32-input GEMM (fallback when ws too small)
// ===========================================================================
template <bool A_BF16, int OUT_MODE>
__global__ __launch_bounds__(256) void gemm_bt_kernel(
    const void* __restrict__ Aptr, const float* __restrict__ Bt,
    const float* __restrict__ bias, void* __restrict__ Cptr, float scale) {
  constexpr int K = 1024, N = 1024;
  constexpr int BM = 128, BK = 32;
  constexpr int LSTR = BK + 8;
  __shared__ __align__(16) bf16 As[BM][LSTR];
  __shared__ __align__(16) bf16 Bs[BM][LSTR];

  const int tid = threadIdx.x;
  const int lane = tid & 63;
  const int w = tid >> 6;
  const int wr = w >> 1, wc = w & 1;
  const int g = lane >> 4, c16 = lane & 15;
  const int row0 = blockIdx.y * BM;
  const int col0 = blockIdx.x * BM;

  f32x4 acc[4][4] = {};

  for (int kt = 0; kt < K / BK; ++kt) {
    const int k0 = kt * BK;
    if constexpr (!A_BF16) {
      const float* A = (const float*)Aptr;
#pragma unroll
      for (int i = 0; i < 4; ++i) {
        const int r = (tid >> 3) + i * 32;
        const int c = (tid & 7) * 4;
        const float4 v = *(const float4*)(&A[(size_t)(row0 + r) * K + k0 + c]);
        bf16x4 hv;
        hv[0] = (bf16)v.x; hv[1] = (bf16)v.y; hv[2] = (bf16)v.z; hv[3] = (bf16)v.w;
        *(bf16x4*)&As[r][c] = hv;
      }
    } else {
      const bf16* A = (const bf16*)Aptr;
#pragma unroll
      for (int i = 0; i < 2; ++i) {
        const int r = (tid >> 2) + i * 64;
        const int c = (tid & 3) * 8;
        *(bf16x8*)&As[r][c] = *(const bf16x8*)(&A[(size_t)(row0 + r) * K + k0 + c]);
      }
    }
#pragma unroll
    for (int i = 0; i < 4; ++i) {
      const int r = (tid >> 3) + i * 32;
      const int c = (tid & 7) * 4;
      const float4 v = *(const float4*)(&Bt[(size_t)(col0 + r) * K + k0 + c]);
      bf16x4 hv;
      hv[0] = (bf16)v.x; hv[1] = (bf16)v.y; hv[2] = (bf16)v.z; hv[3] = (bf16)v.w;
      *(bf16x4*)&Bs[r][c] = hv;
    }
    __syncthreads();

    bf16x8 a[4], b[4];
#pragma unroll
    for (int m = 0; m < 4; ++m)
      a[m] = *(bf16x8*)&As[wr * 64 + m * 16 + c16][g * 8];
#pragma unroll
    for (int n = 0; n < 4; ++n)
      b[n] = *(bf16x8*)&Bs[wc * 64 + n * 16 + c16][g * 8];
#pragma unroll
    for (int m = 0; m < 4; ++m)
#pragma unroll
      for (int n = 0; n < 4; ++n)
        acc[m][n] = __builtin_amdgcn_mfma_f32_16x16x32_bf16(a[m], b[n], acc[m][n], 0, 0, 0);
    __syncthreads();
  }

#pragma unroll
  for (int m = 0; m < 4; ++m) {
#pragma unroll
    for (int n = 0; n < 4; ++n) {
      const int col = col0 + wc * 64 + n * 16 + c16;
      if constexpr (OUT_MODE == 2) {
        const int row = row0 + wr * 64 + m * 16 + g * 4;
        const int bb = row >> 11, s = row & 2047;
        const int hh = col >> 6, j = col & 63;
        bf16x4 hv;
#pragma unroll
        for (int r = 0; r < 4; ++r)
          hv[r] = (bf16)((acc[m][n][r] + bias[col]) * scale);
        *(bf16x4*)&((bf16*)Cptr)[(((size_t)bb * 16 + hh) * 64 + j) * 2048 + s] = hv;
      } else {
#pragma unroll
        for (int r = 0; r < 4; ++r) {
          const int row = row0 + wr * 64 + m * 16 + g * 4 + r;
          const float v = (acc[m][n][r] + bias[col]) * scale;
          if constexpr (OUT_MODE == 1) {
            const int bb = row >> 11, s = row & 2047;
            const int hh = col >> 6, j = col & 63;
            ((bf16*)Cptr)[(((size_t)bb * 16 + hh) * 2048 + s) * 64 + j] = (bf16)v;
          } else {
            ((float*)Cptr)[(size_t)row * N + col] = v;
          }
        }
      }
    }
  }
}

// ===========================================================================
// Causal flash attention, swapped-QK^T, KVB=128, 32 q-rows/wave (2 halves).
// Each kf/bv LDS read feeds TWO MFMAs (half A rows q0w..+15, half B +16..+31)
// -> b128-class LDS reads per 32 q-rows drop 72 -> 40 (the LDS pipe is the
// measured bottleneck). Block = 4 waves x 32 rows = 128 rows; grid (32 bh,
// 16 p) = 512 blocks, y-perm p = y<8?y:23-y. Both halves' diagonals are in
// the block's last tile. Softmax/defer-max per half. LDS 70.7 KB (2 blk/CU).
// ===========================================================================
__global__ __launch_bounds__(256) void attn_kernel(
    const bf16* __restrict__ Q, const bf16* __restrict__ Kb,
    const bf16* __restrict__ Vt, bf16* __restrict__ ctx) {
  constexpr int S = 2048, HD = 64, KVB = 128;
  constexpr int KP = HD + 8;    // 72
  constexpr int VP = KVB + 8;   // 136
  __shared__ __align__(16) bf16 Ks[KVB][KP];
  __shared__ __align__(16) bf16 Vs[HD][VP];
  __shared__ __align__(16) bf16 PT[4][2][16][VP];

  const int tid = threadIdx.x;
  const int lane = tid & 63;
  const int w = tid >> 6;
  const int g = lane >> 4, c16 = lane & 15;
  const int bh = blockIdx.x;
  const int b = bh >> 4, h = bh & 15;

  const int y = blockIdx.y;      // 0..15
  const int p = (y < 8) ? y : 23 - y;

  const bf16* Qh = Q + (size_t)bh * S * HD;
  const bf16* Kh = Kb + (size_t)bh * S * HD;
  const bf16* Vh = Vt + (size_t)bh * HD * S;

  // staging: K 128x64 (2 thr/row, 32 elems), V^T 64x128 (4 thr/row, 32 elems)
  const int srK = tid >> 1, scK = (tid & 1) * 32;
  const int srV = tid >> 2, scV = (tid & 3) * 32;

  const int q0w = p * 128 + w * 32;  // wave's first q row (32 rows: A=+0..15, B=+16..31)
  const int nt = p + 1;              // 128-wide KV tiles

  // Q fragments for both halves
  bf16x8 qfA[2], qfB[2];
#pragma unroll
  for (int ks = 0; ks < 2; ++ks) {
    qfA[ks] = *(const bf16x8*)&Qh[(size_t)(q0w + c16) * HD + ks * 32 + g * 8];
    qfB[ks] = *(const bf16x8*)&Qh[(size_t)(q0w + 16 + c16) * HD + ks * 32 + g * 8];
  }

  f32x4 oaccA[4] = {}, oaccB[4] = {};
  float mA = -1e30f, lA = 0.f, mB = -1e30f, lB = 0.f;

  // prologue: tile 0 into regs
  bf16x8 kr[4], vr[4];
#pragma unroll
  for (int i = 0; i < 4; ++i)
    kr[i] = *(const bf16x8*)&Kh[(size_t)srK * HD + scK + i * 8];
#pragma unroll
  for (int i = 0; i < 4; ++i)
    vr[i] = *(const bf16x8*)&Vh[(size_t)srV * S + scV + i * 8];

#pragma unroll 1
  for (int kt = 0; kt < nt; ++kt) {
    __syncthreads();
#pragma unroll
    for (int i = 0; i < 4; ++i)
      *(bf16x8*)&Ks[srK][scK + i * 8] = kr[i];
#pragma unroll
    for (int i = 0; i < 4; ++i)
      *(bf16x8*)&Vs[srV][scV + i * 8] = vr[i];
    __syncthreads();

    const int kv0 = kt * KVB;
    if (kt + 1 < nt) {
      const int nkv = kv0 + KVB;
#pragma unroll
      for (int i = 0; i < 4; ++i)
        kr[i] = *(const bf16x8*)&Kh[(size_t)(nkv + srK) * HD + scK + i * 8];
#pragma unroll
      for (int i = 0; i < 4; ++i)
        vr[i] = *(const bf16x8*)&Vh[(size_t)srV * S + nkv + scV + i * 8];
    }

    // ---- S^T = K Q^T, both halves share each kf read ----
    f32x4 scA[8] = {}, scB[8] = {};
    __builtin_amdgcn_s_setprio(1);
#pragma unroll
    for (int ks = 0; ks < 2; ++ks) {
#pragma unroll
      for (int ni = 0; ni < 8; ++ni) {
        const bf16x8 kf = *(const bf16x8*)&Ks[ni * 16 + c16][ks * 32 + g * 8];
        scA[ni] = __builtin_amdgcn_mfma_f32_16x16x32_bf16(kf, qfA[ks], scA[ni], 0, 0, 0);
        scB[ni] = __builtin_amdgcn_mfma_f32_16x16x32_bf16(kf, qfB[ks], scB[ni], 0, 0, 0);
      }
    }
    __builtin_amdgcn_s_setprio(0);

    // ---- causal mask (last tile only) ----
    if (kt == nt - 1) {
      const int qqA = q0w + c16;
      const int qqB = q0w + 16 + c16;
#pragma unroll
      for (int ni = 0; ni < 8; ++ni)
#pragma unroll
        for (int r = 0; r < 4; ++r) {
          const int kv = kv0 + ni * 16 + g * 4 + r;
          if (kv > qqA) scA[ni][r] = -1e30f;
          if (kv > qqB) scB[ni][r] = -1e30f;
        }
    }

    // ---- online softmax, half A ----
    {
      float t = -1e30f;
#pragma unroll
      for (int ni = 0; ni < 8; ++ni)
#pragma unroll
        for (int r = 0; r < 4; ++r) t = fmaxf(t, scA[ni][r]);
      t = fmaxf(t, __shfl_xor(t, 16));
      t = fmaxf(t, __shfl_xor(t, 32));
      if (!__all(t <= mA + 8.0f)) {
        const float mnew = fmaxf(mA, t);
        const float corr = exp2f(mA - mnew);
        mA = mnew;
        lA *= corr;
        float cb[4];
#pragma unroll
        for (int r = 0; r < 4; ++r)
          cb[r] = __shfl(corr, (lane & 48) + g * 4 + r);
#pragma unroll
        for (int nd = 0; nd < 4; ++nd)
#pragma unroll
          for (int r = 0; r < 4; ++r) oaccA[nd][r] *= cb[r];
      }
      float rs = 0.f;
#pragma unroll
      for (int ni = 0; ni < 8; ++ni)
#pragma unroll
        for (int r = 0; r < 4; ++r) {
          scA[ni][r] = exp2f(scA[ni][r] - mA);
          rs += scA[ni][r];
        }
      rs += __shfl_xor(rs, 16);
      rs += __shfl_xor(rs, 32);
      lA += rs;
#pragma unroll
      for (int ni = 0; ni < 8; ++ni) {
        bf16x4 hv;
#pragma unroll
        for (int r = 0; r < 4; ++r) hv[r] = (bf16)scA[ni][r];
        *(bf16x4*)&PT[w][0][c16][ni * 16 + g * 4] = hv;
      }
    }

    // ---- online softmax, half B ----
    {
      float t = -1e30f;
#pragma unroll
      for (int ni = 0; ni < 8; ++ni)
#pragma unroll
        for (int r = 0; r < 4; ++r) t = fmaxf(t, scB[ni][r]);
      t = fmaxf(t, __shfl_xor(t, 16));
      t = fmaxf(t, __shfl_xor(t, 32));
      if (!__all(t <= mB + 8.0f)) {
        const float mnew = fmaxf(mB, t);
        const float corr = exp2f(mB - mnew);
        mB = mnew;
        lB *= corr;
        float cb[4];
#pragma unroll
        for (int r = 0; r < 4; ++r)
          cb[r] = __shfl(corr, (lane & 48) + g * 4 + r);
#pragma unroll
        for (int nd = 0; nd < 4; ++nd)
#pragma unroll
          for (int r = 0; r < 4; ++r) oaccB[nd][r] *= cb[r];
      }
      float rs = 0.f;
#pragma unroll
      for (int ni = 0; ni < 8; ++ni)
#pragma unroll
        for (int r = 0; r < 4; ++r) {
          scB[ni][r] = exp2f(scB[ni][r] - mB);
          rs += scB[ni][r];
        }
      rs += __shfl_xor(rs, 16);
      rs += __shfl_xor(rs, 32);
      lB += rs;
#pragma unroll
      for (int ni = 0; ni < 8; ++ni) {
        bf16x4 hv;
#pragma unroll
        for (int r = 0; r < 4; ++r) hv[r] = (bf16)scB[ni][r];
        *(bf16x4*)&PT[w][1][c16][ni * 16 + g * 4] = hv;
      }
    }

    // ---- O += P V, both halves share each bv read ----
    __builtin_amdgcn_s_setprio(1);
#pragma unroll
    for (int ks = 0; ks < 4; ++ks) {
      const bf16x8 paA = *(const bf16x8*)&PT[w][0][c16][ks * 32 + g * 8];
      const bf16x8 paB = *(const bf16x8*)&PT[w][1][c16][ks * 32 + g * 8];
#pragma unroll
      for (int nd = 0; nd < 4; ++nd) {
        const bf16x8 bv = *(const bf16x8*)&Vs[nd * 16 + c16][ks * 32 + g * 8];
        oaccA[nd] = __builtin_amdgcn_mfma_f32_16x16x32_bf16(paA, bv, oaccA[nd], 0, 0, 0);
        oaccB[nd] = __builtin_amdgcn_mfma_f32_16x16x32_bf16(paB, bv, oaccB[nd], 0, 0, 0);
      }
    }
    __builtin_amdgcn_s_setprio(0);
  }

  // ---- epilogue: both halves ----
  float lbA[4], lbB[4];
#pragma unroll
  for (int r = 0; r < 4; ++r) {
    lbA[r] = __shfl(lA, (lane & 48) + g * 4 + r);
    lbB[r] = __shfl(lB, (lane & 48) + g * 4 + r);
  }
#pragma unroll
  for (int nd = 0; nd < 4; ++nd)
#pragma unroll
    for (int r = 0; r < 4; ++r) {
      const int qA = q0w + g * 4 + r;
      const int qB = q0w + 16 + g * 4 + r;
      const int col = h * 64 + nd * 16 + c16;
      ctx[((size_t)b * S + qA) * 1024 + col] = (bf16)(oaccA[nd][r] / lbA[r]);
      ctx[((size_t)b * S + qB) * 1024 + col] = (bf16)(oaccB[nd][r] / lbB[r]);
    }
}

// ===========================================================================
extern "C" void kernel_launch(void* const* d_in, const int* in_sizes, int n_in,
                              void* d_out, int out_size, void* d_ws, size_t ws_size,
                              hipStream_t stream) {
  (void)in_sizes; (void)n_in; (void)out_size;
  const float* query = (const float*)d_in[0];
  const float* key   = (const float*)d_in[1];
  const float* value = (const float*)d_in[2];
  // d_in[3] = attn_mask (causal triu) — structural, not read
  const float* q_w = (const float*)d_in[4];
  const float* q_b = (const float*)d_in[5];
  const float* k_w = (const float*)d_in[6];
  const float* k_b = (const float*)d_in[7];
  const float* v_w = (const float*)d_in[8];
  const float* v_b = (const float*)d_in[9];
  const float* o_w = (const float*)d_in[10];
  const float* o_b = (const float*)d_in[11];

  const size_t NELEM = (size_t)4096 * 1024;  // B*S*D
  const size_t WELEM = (size_t)1024 * 1024;
  bf16* Qbuf = (bf16*)d_ws;        //  0 MB
  bf16* Kbuf = Qbuf + NELEM;       //  8 MB
  bf16* Vbuf = Kbuf + NELEM;       // 16 MB  [B,H,hd,S]
  bf16* ctxb = Vbuf + NELEM;       // 24 MB

  const dim3 blk(256);
  const float QSCALE = 0.125f * 1.44269504088896f;  // 1/sqrt(64) * log2(e)

  const size_t need = 64ull * 1024 * 1024;
  if (ws_size >= need) {
    // ---- fast path: pre-convert everything to bf16, pipelined GEMMs
    bf16* qbf  = ctxb + NELEM;       // 32 MB
    bf16* kbf  = qbf + NELEM;        // 40 MB
    bf16* vbf  = kbf + NELEM;        // 48 MB
    bf16* qwbf = vbf + NELEM;        // 56 MB
    bf16* kwbf = qwbf + WELEM;       // 58 MB
    bf16* vwbf = kwbf + WELEM;       // 60 MB
    bf16* owbf = vwbf + WELEM;       // 62 MB .. 64 MB

    CvtArgs ca;
    ca.src[0] = query; ca.dst[0] = qbf;  ca.n4[0] = (int)(NELEM / 4);
    ca.src[1] = key;   ca.dst[1] = kbf;  ca.n4[1] = (int)(NELEM / 4);
    ca.src[2] = value; ca.dst[2] = vbf;  ca.n4[2] = (int)(NELEM / 4);
    ca.src[3] = q_w;   ca.dst[3] = qwbf; ca.n4[3] = (int)(WELEM / 4);
    ca.src[4] = k_w;   ca.dst[4] = kwbf; ca.n4[4] = (int)(WELEM / 4);
    ca.src[5] = v_w;   ca.dst[5] = vwbf; ca.n4[5] = (int)(WELEM / 4);
    ca.src[6] = o_w;   ca.dst[6] = owbf; ca.n4[6] = (int)(WELEM / 4);
    cvt_kernel<<<dim3(256, 7), blk, 0, stream>>>(ca);

    qkv_gemm_kernel<<<dim3(8, 32, 3), blk, 0, stream>>>(
        qbf, kbf, vbf, qwbf, kwbf, vwbf, q_b, k_b, v_b, Qbuf, Kbuf, Vbuf, QSCALE);

    attn_kernel<<<dim3(32, 16), blk, 0, stream>>>(Qbuf, Kbuf, Vbuf, ctxb);

    o_gemm_kernel<<<dim3(16, 32), blk, 0, stream>>>(ctxb, owbf, o_b, (float*)d_out);
  } else {
    // ---- fallback: fp32-input reg-staged GEMMs
    const dim3 ggrid(8, 32);
    gemm_bt_kernel<false, 1><<<ggrid, blk, 0, stream>>>(query, q_w, q_b, Qbuf, QSCALE);
    gemm_bt_kernel<false, 1><<<ggrid, blk, 0, stream>>>(key, k_w, k_b, Kbuf, 1.0f);
    gemm_bt_kernel<false, 2><<<ggrid, blk, 0, stream>>>(value, v_w, v_b, Vbuf, 1.0f);
    attn_kernel<<<dim3(32, 16), blk, 0, stream>>>(Qbuf, Kbuf, Vbuf, ctxb);
    gemm_bt_kernel<true, 0><<<ggrid, blk, 0, stream>>>(ctxb, o_w, o_b, d_out, 1.0f);
  }
}

// Round 19
// 118.748 us; speedup vs baseline: 1.1023x; 1.1023x over previous
//
#include <hip/hip_runtime.h>
#include <hip/hip_bf16.h>

typedef __bf16 bf16;
typedef __attribute__((ext_vector_type(8))) __bf16 bf16x8;
typedef __attribute__((ext_vector_type(4))) __bf16 bf16x4;
typedef __attribute__((ext_vector_type(4))) float f32x4;

// ===========================================================================
// fp32 -> bf16 conversion pass (7 segments in one launch)
// ===========================================================================
struct CvtArgs {
  const float* src[7];
  bf16* dst[7];
  int n4[7];  // element count / 4
};

__global__ __launch_bounds__(256) void cvt_kernel(CvtArgs a) {
  const int seg = blockIdx.y;
  const float4* s = (const float4*)a.src[seg];
  bf16x4* d = (bf16x4*)a.dst[seg];
  const int n = a.n4[seg];
  const int stride = gridDim.x * 256;
  for (int i = blockIdx.x * 256 + threadIdx.x; i < n; i += stride) {
    const float4 v = s[i];
    bf16x4 h;
    h[0] = (bf16)v.x; h[1] = (bf16)v.y; h[2] = (bf16)v.z; h[3] = (bf16)v.w;
    d[i] = h;
  }
}

// ===========================================================================
// gload16: async global->LDS 16B per lane
// ===========================================================================
__device__ __forceinline__ void gload16(const void* g, void* l) {
  __builtin_amdgcn_global_load_lds(
      (const __attribute__((address_space(1))) void*)g,
      (__attribute__((address_space(3))) void*)l, 16, 0, 0);
}

// ===========================================================================
// bf16 GEMM, counted-vmcnt triple-buffered pipeline, 128x128 tile (qkv).
// ===========================================================================
__device__ __forceinline__ void gemm_core2(const bf16* __restrict__ A,
                                           const bf16* __restrict__ W,
                                           const float* __restrict__ bias,
                                           void* __restrict__ C,
                                           float scale, int mode,
                                           int bx, int by) {
  constexpr int K = 1024, N = 1024, BK = 32, NT = K / BK;
  __shared__ __align__(16) bf16 As[3][128 * BK];
  __shared__ __align__(16) bf16 Bs[3][128 * BK];

  const int tid = threadIdx.x;
  const int lane = tid & 63;
  const int w = tid >> 6;
  const int wm = w >> 1, wn = w & 1;
  const int g = lane >> 4, c16 = lane & 15;
  const int row0 = by * 128;
  const int col0 = bx * 128;

  const int sr = tid >> 2;
  const int ssw = ((tid & 3) ^ (sr & 3)) * 8;
  const int sdst = tid * 8;

  const int aoff = (wm * 64 + c16) * BK + ((g ^ (c16 & 3)) * 8);
  const int boff = (wn * 64 + c16) * BK + ((g ^ (c16 & 3)) * 8);

  f32x4 acc[4][4] = {};

#define STAGE2(buf, kt)                                                          \
  {                                                                              \
    const int k0_ = (kt)*BK;                                                     \
    gload16(&A[(size_t)(row0 + sr) * K + k0_ + ssw], &As[buf][sdst]);            \
    gload16(&A[(size_t)(row0 + 64 + sr) * K + k0_ + ssw], &As[buf][2048 + sdst]);\
    gload16(&W[(size_t)(col0 + sr) * K + k0_ + ssw], &Bs[buf][sdst]);            \
    gload16(&W[(size_t)(col0 + 64 + sr) * K + k0_ + ssw], &Bs[buf][2048 + sdst]);\
  }

  STAGE2(0, 0);
  STAGE2(1, 1);

#pragma unroll 1
  for (int kt = 0; kt < NT; ++kt) {
    const int cur = kt % 3;
    if (kt == NT - 1)
      asm volatile("s_waitcnt vmcnt(0)" ::: "memory");
    else
      asm volatile("s_waitcnt vmcnt(4)" ::: "memory");
    __builtin_amdgcn_s_barrier();
    __builtin_amdgcn_sched_barrier(0);

    if (kt + 2 < NT) {
      const int nb = (cur + 2 >= 3) ? cur - 1 : cur + 2;
      STAGE2(nb, kt + 2);
    }

    bf16x8 a[4], b[4];
#pragma unroll
    for (int m = 0; m < 4; ++m) a[m] = *(const bf16x8*)&As[cur][aoff + m * 512];
#pragma unroll
    for (int n = 0; n < 4; ++n) b[n] = *(const bf16x8*)&Bs[cur][boff + n * 512];

    __builtin_amdgcn_s_setprio(1);
#pragma unroll
    for (int m = 0; m < 4; ++m)
#pragma unroll
      for (int n = 0; n < 4; ++n)
        acc[m][n] = __builtin_amdgcn_mfma_f32_16x16x32_bf16(a[m], b[n], acc[m][n], 0, 0, 0);
    __builtin_amdgcn_s_setprio(0);
  }
#undef STAGE2

#pragma unroll
  for (int m = 0; m < 4; ++m) {
#pragma unroll
    for (int n = 0; n < 4; ++n) {
      const int col = col0 + wn * 64 + n * 16 + c16;
      if (mode == 2) {
        const int row = row0 + wm * 64 + m * 16 + g * 4;
        const int bb = row >> 11, s = row & 2047;
        const int hh = col >> 6, j = col & 63;
        bf16x4 hv;
#pragma unroll
        for (int r = 0; r < 4; ++r)
          hv[r] = (bf16)((acc[m][n][r] + bias[col]) * scale);
        *(bf16x4*)&((bf16*)C)[(((size_t)bb * 16 + hh) * 64 + j) * 2048 + s] = hv;
      } else {
#pragma unroll
        for (int r = 0; r < 4; ++r) {
          const int row = row0 + wm * 64 + m * 16 + g * 4 + r;
          const float v = (acc[m][n][r] + bias[col]) * scale;
          if (mode == 1) {
            const int bb = row >> 11, s = row & 2047;
            const int hh = col >> 6, j = col & 63;
            ((bf16*)C)[(((size_t)bb * 16 + hh) * 2048 + s) * 64 + j] = (bf16)v;
          } else {
            ((float*)C)[(size_t)row * N + col] = v;
          }
        }
      }
    }
  }
}

// ===========================================================================
// bf16 GEMM, counted pipeline, 128x64 tile (o_gemm): 512 blocks, 2/CU.
// ===========================================================================
__device__ __forceinline__ void gemm_core3(const bf16* __restrict__ A,
                                           const bf16* __restrict__ W,
                                           const float* __restrict__ bias,
                                           float* __restrict__ C,
                                           int bx, int by) {
  constexpr int K = 1024, N = 1024, BK = 32, NT = K / BK;
  __shared__ __align__(16) bf16 As[3][128 * BK];
  __shared__ __align__(16) bf16 Bs[3][64 * BK];

  const int tid = threadIdx.x;
  const int lane = tid & 63;
  const int w = tid >> 6;
  const int wm = w >> 1, wn = w & 1;
  const int g = lane >> 4, c16 = lane & 15;
  const int row0 = by * 128;
  const int col0 = bx * 64;

  const int sr = tid >> 2;
  const int ssw = ((tid & 3) ^ (sr & 3)) * 8;
  const int sdst = tid * 8;

  const int aoff = (wm * 64 + c16) * BK + ((g ^ (c16 & 3)) * 8);
  const int boff = (wn * 32 + c16) * BK + ((g ^ (c16 & 3)) * 8);

  f32x4 acc[4][2] = {};

#define STAGE3(buf, kt)                                                          \
  {                                                                              \
    const int k0_ = (kt)*BK;                                                     \
    gload16(&A[(size_t)(row0 + sr) * K + k0_ + ssw], &As[buf][sdst]);            \
    gload16(&A[(size_t)(row0 + 64 + sr) * K + k0_ + ssw], &As[buf][2048 + sdst]);\
    gload16(&W[(size_t)(col0 + sr) * K + k0_ + ssw], &Bs[buf][sdst]);            \
  }

  STAGE3(0, 0);
  STAGE3(1, 1);

#pragma unroll 1
  for (int kt = 0; kt < NT; ++kt) {
    const int cur = kt % 3;
    if (kt == NT - 1)
      asm volatile("s_waitcnt vmcnt(0)" ::: "memory");
    else
      asm volatile("s_waitcnt vmcnt(3)" ::: "memory");
    __builtin_amdgcn_s_barrier();
    __builtin_amdgcn_sched_barrier(0);

    if (kt + 2 < NT) {
      const int nb = (cur + 2 >= 3) ? cur - 1 : cur + 2;
      STAGE3(nb, kt + 2);
    }

    bf16x8 a[4], b[2];
#pragma unroll
    for (int m = 0; m < 4; ++m) a[m] = *(const bf16x8*)&As[cur][aoff + m * 512];
#pragma unroll
    for (int n = 0; n < 2; ++n) b[n] = *(const bf16x8*)&Bs[cur][boff + n * 512];

    __builtin_amdgcn_s_setprio(1);
#pragma unroll
    for (int m = 0; m < 4; ++m)
#pragma unroll
      for (int n = 0; n < 2; ++n)
        acc[m][n] = __builtin_amdgcn_mfma_f32_16x16x32_bf16(a[m], b[n], acc[m][n], 0, 0, 0);
    __builtin_amdgcn_s_setprio(0);
  }
#undef STAGE3

#pragma unroll
  for (int m = 0; m < 4; ++m) {
#pragma unroll
    for (int n = 0; n < 2; ++n) {
      const int col = col0 + wn * 32 + n * 16 + c16;
#pragma unroll
      for (int r = 0; r < 4; ++r) {
        const int row = row0 + wm * 64 + m * 16 + g * 4 + r;
        C[(size_t)row * N + col] = acc[m][n][r] + bias[col];
      }
    }
  }
}

__device__ __forceinline__ void xcd_swz(int& bx, int& by, int& bz) {
  const int lid = ((int)blockIdx.z * 32 + (int)blockIdx.y) * 8 + (int)blockIdx.x;
  const int cpx = ((int)gridDim.z * 256) >> 3;
  int s = (lid & 7) * cpx + (lid >> 3);
  bx = s & 7;
  by = (s >> 3) & 31;
  bz = s >> 8;
}

__device__ __forceinline__ void xcd_swz2(int& bx, int& by) {
  const int gx = (int)gridDim.x;
  const int total = gx * (int)gridDim.y;
  const int lid = (int)blockIdx.y * gx + (int)blockIdx.x;
  const int cpx = total >> 3;
  const int s = (lid & 7) * cpx + (lid >> 3);
  bx = s & (gx - 1);
  by = s / gx;
}

__global__ __launch_bounds__(256, 3) void qkv_gemm_kernel(
    const bf16* __restrict__ qa, const bf16* __restrict__ ka, const bf16* __restrict__ va,
    const bf16* __restrict__ qw, const bf16* __restrict__ kw, const bf16* __restrict__ vw,
    const float* __restrict__ qb, const float* __restrict__ kb, const float* __restrict__ vb,
    bf16* __restrict__ Qo, bf16* __restrict__ Ko, bf16* __restrict__ Vo, float qscale) {
  int bx, by, bz;
  xcd_swz(bx, by, bz);
  const bf16* A = (bz == 0) ? qa : (bz == 1) ? ka : va;
  const bf16* W = (bz == 0) ? qw : (bz == 1) ? kw : vw;
  const float* bias = (bz == 0) ? qb : (bz == 1) ? kb : vb;
  bf16* C = (bz == 0) ? Qo : (bz == 1) ? Ko : Vo;
  const float scale = (bz == 0) ? qscale : 1.0f;
  const int mode = (bz == 2) ? 2 : 1;
  gemm_core2(A, W, bias, C, scale, mode, bx, by);
}

__global__ __launch_bounds__(256, 4) void o_gemm_kernel(
    const bf16* __restrict__ A, const bf16* __restrict__ W,
    const float* __restrict__ bias, float* __restrict__ C) {
  int bx, by;
  xcd_swz2(bx, by);
  gemm_core3(A, W, bias, C, bx, by);
}

// ===========================================================================
// Legacy fp32-input GEMM (fallback when ws too small)
// ===========================================================================
template <bool A_BF16, int OUT_MODE>
__global__ __launch_bounds__(256) void gemm_bt_kernel(
    const void* __restrict__ Aptr, const float* __restrict__ Bt,
    const float* __restrict__ bias, void* __restrict__ Cptr, float scale) {
  constexpr int K = 1024, N = 1024;
  constexpr int BM = 128, BK = 32;
  constexpr int LSTR = BK + 8;
  __shared__ __align__(16) bf16 As[BM][LSTR];
  __shared__ __align__(16) bf16 Bs[BM][LSTR];

  const int tid = threadIdx.x;
  const int lane = tid & 63;
  const int w = tid >> 6;
  const int wr = w >> 1, wc = w & 1;
  const int g = lane >> 4, c16 = lane & 15;
  const int row0 = blockIdx.y * BM;
  const int col0 = blockIdx.x * BM;

  f32x4 acc[4][4] = {};

  for (int kt = 0; kt < K / BK; ++kt) {
    const int k0 = kt * BK;
    if constexpr (!A_BF16) {
      const float* A = (const float*)Aptr;
#pragma unroll
      for (int i = 0; i < 4; ++i) {
        const int r = (tid >> 3) + i * 32;
        const int c = (tid & 7) * 4;
        const float4 v = *(const float4*)(&A[(size_t)(row0 + r) * K + k0 + c]);
        bf16x4 hv;
        hv[0] = (bf16)v.x; hv[1] = (bf16)v.y; hv[2] = (bf16)v.z; hv[3] = (bf16)v.w;
        *(bf16x4*)&As[r][c] = hv;
      }
    } else {
      const bf16* A = (const bf16*)Aptr;
#pragma unroll
      for (int i = 0; i < 2; ++i) {
        const int r = (tid >> 2) + i * 64;
        const int c = (tid & 3) * 8;
        *(bf16x8*)&As[r][c] = *(const bf16x8*)(&A[(size_t)(row0 + r) * K + k0 + c]);
      }
    }
#pragma unroll
    for (int i = 0; i < 4; ++i) {
      const int r = (tid >> 3) + i * 32;
      const int c = (tid & 7) * 4;
      const float4 v = *(const float4*)(&Bt[(size_t)(col0 + r) * K + k0 + c]);
      bf16x4 hv;
      hv[0] = (bf16)v.x; hv[1] = (bf16)v.y; hv[2] = (bf16)v.z; hv[3] = (bf16)v.w;
      *(bf16x4*)&Bs[r][c] = hv;
    }
    __syncthreads();

    bf16x8 a[4], b[4];
#pragma unroll
    for (int m = 0; m < 4; ++m)
      a[m] = *(bf16x8*)&As[wr * 64 + m * 16 + c16][g * 8];
#pragma unroll
    for (int n = 0; n < 4; ++n)
      b[n] = *(bf16x8*)&Bs[wc * 64 + n * 16 + c16][g * 8];
#pragma unroll
    for (int m = 0; m < 4; ++m)
#pragma unroll
      for (int n = 0; n < 4; ++n)
        acc[m][n] = __builtin_amdgcn_mfma_f32_16x16x32_bf16(a[m], b[n], acc[m][n], 0, 0, 0);
    __syncthreads();
  }

#pragma unroll
  for (int m = 0; m < 4; ++m) {
#pragma unroll
    for (int n = 0; n < 4; ++n) {
      const int col = col0 + wc * 64 + n * 16 + c16;
      if constexpr (OUT_MODE == 2) {
        const int row = row0 + wr * 64 + m * 16 + g * 4;
        const int bb = row >> 11, s = row & 2047;
        const int hh = col >> 6, j = col & 63;
        bf16x4 hv;
#pragma unroll
        for (int r = 0; r < 4; ++r)
          hv[r] = (bf16)((acc[m][n][r] + bias[col]) * scale);
        *(bf16x4*)&((bf16*)Cptr)[(((size_t)bb * 16 + hh) * 64 + j) * 2048 + s] = hv;
      } else {
#pragma unroll
        for (int r = 0; r < 4; ++r) {
          const int row = row0 + wr * 64 + m * 16 + g * 4 + r;
          const float v = (acc[m][n][r] + bias[col]) * scale;
          if constexpr (OUT_MODE == 1) {
            const int bb = row >> 11, s = row & 2047;
            const int hh = col >> 6, j = col & 63;
            ((bf16*)Cptr)[(((size_t)bb * 16 + hh) * 2048 + s) * 64 + j] = (bf16)v;
          } else {
            ((float*)Cptr)[(size_t)row * N + col] = v;
          }
        }
      }
    }
  }
}

// ===========================================================================
// Causal flash attention, swapped-QK^T, KVB=128 (round 13 inner loop —
// empirical best across 11 structural variants: 52.1-52.4 µs).
// ===========================================================================
__global__ __launch_bounds__(256) void attn_kernel(
    const bf16* __restrict__ Q, const bf16* __restrict__ Kb,
    const bf16* __restrict__ Vt, bf16* __restrict__ ctx) {
  constexpr int S = 2048, HD = 64, KVB = 128;
  constexpr int KP = HD + 8;    // 72
  constexpr int VP = KVB + 8;   // 136
  __shared__ __align__(16) bf16 Ks[KVB][KP];
  __shared__ __align__(16) bf16 Vs[HD][VP];
  __shared__ __align__(16) bf16 PT[4][16][VP];

  const int tid = threadIdx.x;
  const int lane = tid & 63;
  const int w = tid >> 6;
  const int g = lane >> 4, c16 = lane & 15;
  const int bh = blockIdx.x;
  const int b = bh >> 4, h = bh & 15;

  const int jj = blockIdx.y;
  const int sub = jj & 7, grp = jj >> 3;
  const int qt = (grp == 0) ? sub : (grp == 1) ? 31 - sub : (grp == 2) ? 8 + sub : 23 - sub;

  const bf16* Qh = Q + (size_t)bh * S * HD;
  const bf16* Kh = Kb + (size_t)bh * S * HD;
  const bf16* Vh = Vt + (size_t)bh * HD * S;

  const int srK = tid >> 1, scK = (tid & 1) * 32;
  const int srV = tid >> 2, scV = (tid & 3) * 32;

  const int q0w = qt * 64 + w * 16;
  const int nt = (qt >> 1) + 1;

  bf16x8 qf[2];
#pragma unroll
  for (int ks = 0; ks < 2; ++ks)
    qf[ks] = *(const bf16x8*)&Qh[(size_t)(q0w + c16) * HD + ks * 32 + g * 8];

  f32x4 oacc[4] = {};
  float m = -1e30f, l = 0.f;

  bf16x8 kr[4], vr[4];
#pragma unroll
  for (int i = 0; i < 4; ++i)
    kr[i] = *(const bf16x8*)&Kh[(size_t)srK * HD + scK + i * 8];
#pragma unroll
  for (int i = 0; i < 4; ++i)
    vr[i] = *(const bf16x8*)&Vh[(size_t)srV * S + scV + i * 8];

#pragma unroll 1
  for (int kt = 0; kt < nt; ++kt) {
    __syncthreads();
#pragma unroll
    for (int i = 0; i < 4; ++i)
      *(bf16x8*)&Ks[srK][scK + i * 8] = kr[i];
#pragma unroll
    for (int i = 0; i < 4; ++i)
      *(bf16x8*)&Vs[srV][scV + i * 8] = vr[i];
    __syncthreads();

    const int kv0 = kt * KVB;
    if (kt + 1 < nt) {
      const int nkv = kv0 + KVB;
#pragma unroll
      for (int i = 0; i < 4; ++i)
        kr[i] = *(const bf16x8*)&Kh[(size_t)(nkv + srK) * HD + scK + i * 8];
#pragma unroll
      for (int i = 0; i < 4; ++i)
        vr[i] = *(const bf16x8*)&Vh[(size_t)srV * S + nkv + scV + i * 8];
    }

    f32x4 sc[8] = {};
    __builtin_amdgcn_s_setprio(1);
#pragma unroll
    for (int ks = 0; ks < 2; ++ks) {
#pragma unroll
      for (int ni = 0; ni < 8; ++ni) {
        const bf16x8 kf = *(const bf16x8*)&Ks[ni * 16 + c16][ks * 32 + g * 8];
        sc[ni] = __builtin_amdgcn_mfma_f32_16x16x32_bf16(kf, qf[ks], sc[ni], 0, 0, 0);
      }
    }
    __builtin_amdgcn_s_setprio(0);

    if (kt == nt - 1) {
      const int qq = q0w + c16;
#pragma unroll
      for (int ni = 0; ni < 8; ++ni)
#pragma unroll
        for (int r = 0; r < 4; ++r) {
          const int kv = kv0 + ni * 16 + g * 4 + r;
          if (kv > qq) sc[ni][r] = -1e30f;
        }
    }

    float t = -1e30f;
#pragma unroll
    for (int ni = 0; ni < 8; ++ni)
#pragma unroll
      for (int r = 0; r < 4; ++r) t = fmaxf(t, sc[ni][r]);
    t = fmaxf(t, __shfl_xor(t, 16));
    t = fmaxf(t, __shfl_xor(t, 32));
    if (!__all(t <= m + 8.0f)) {
      const float mnew = fmaxf(m, t);
      const float corr = exp2f(m - mnew);
      m = mnew;
      l *= corr;
      float cb[4];
#pragma unroll
      for (int r = 0; r < 4; ++r)
        cb[r] = __shfl(corr, (lane & 48) + g * 4 + r);
#pragma unroll
      for (int nd = 0; nd < 4; ++nd)
#pragma unroll
        for (int r = 0; r < 4; ++r) oacc[nd][r] *= cb[r];
    }
    float rs = 0.f;
#pragma unroll
    for (int ni = 0; ni < 8; ++ni)
#pragma unroll
      for (int r = 0; r < 4; ++r) {
        sc[ni][r] = exp2f(sc[ni][r] - m);
        rs += sc[ni][r];
      }
    rs += __shfl_xor(rs, 16);
    rs += __shfl_xor(rs, 32);
    l += rs;

#pragma unroll
    for (int ni = 0; ni < 8; ++ni) {
      bf16x4 hv;
#pragma unroll
      for (int r = 0; r < 4; ++r) hv[r] = (bf16)sc[ni][r];
      *(bf16x4*)&PT[w][c16][ni * 16 + g * 4] = hv;
    }

    __builtin_amdgcn_s_setprio(1);
#pragma unroll
    for (int ks = 0; ks < 4; ++ks) {
      const bf16x8 pa = *(const bf16x8*)&PT[w][c16][ks * 32 + g * 8];
#pragma unroll
      for (int nd = 0; nd < 4; ++nd) {
        const bf16x8 bv = *(const bf16x8*)&Vs[nd * 16 + c16][ks * 32 + g * 8];
        oacc[nd] = __builtin_amdgcn_mfma_f32_16x16x32_bf16(pa, bv, oacc[nd], 0, 0, 0);
      }
    }
    __builtin_amdgcn_s_setprio(0);
  }

  float lb[4];
#pragma unroll
  for (int r = 0; r < 4; ++r)
    lb[r] = __shfl(l, (lane & 48) + g * 4 + r);
#pragma unroll
  for (int nd = 0; nd < 4; ++nd)
#pragma unroll
    for (int r = 0; r < 4; ++r) {
      const int q = q0w + g * 4 + r;
      const int col = h * 64 + nd * 16 + c16;
      ctx[((size_t)b * S + q) * 1024 + col] = (bf16)(oacc[nd][r] / lb[r]);
    }
}

// ===========================================================================
extern "C" void kernel_launch(void* const* d_in, const int* in_sizes, int n_in,
                              void* d_out, int out_size, void* d_ws, size_t ws_size,
                              hipStream_t stream) {
  (void)in_sizes; (void)n_in; (void)out_size;
  const float* query = (const float*)d_in[0];
  const float* key   = (const float*)d_in[1];
  const float* value = (const float*)d_in[2];
  // d_in[3] = attn_mask (causal triu) — structural, not read
  const float* q_w = (const float*)d_in[4];
  const float* q_b = (const float*)d_in[5];
  const float* k_w = (const float*)d_in[6];
  const float* k_b = (const float*)d_in[7];
  const float* v_w = (const float*)d_in[8];
  const float* v_b = (const float*)d_in[9];
  const float* o_w = (const float*)d_in[10];
  const float* o_b = (const float*)d_in[11];

  const size_t NELEM = (size_t)4096 * 1024;  // B*S*D
  const size_t WELEM = (size_t)1024 * 1024;
  bf16* Qbuf = (bf16*)d_ws;        //  0 MB
  bf16* Kbuf = Qbuf + NELEM;       //  8 MB
  bf16* Vbuf = Kbuf + NELEM;       // 16 MB  [B,H,hd,S]
  bf16* ctxb = Vbuf + NELEM;       // 24 MB

  const dim3 blk(256);
  const float QSCALE = 0.125f * 1.44269504088896f;  // 1/sqrt(64) * log2(e)

  const size_t need = 64ull * 1024 * 1024;
  if (ws_size >= need) {
    // ---- fast path: pre-convert everything to bf16, pipelined GEMMs
    bf16* qbf  = ctxb + NELEM;       // 32 MB
    bf16* kbf  = qbf + NELEM;        // 40 MB
    bf16* vbf  = kbf + NELEM;        // 48 MB
    bf16* qwbf = vbf + NELEM;        // 56 MB
    bf16* kwbf = qwbf + WELEM;       // 58 MB
    bf16* vwbf = kwbf + WELEM;       // 60 MB
    bf16* owbf = vwbf + WELEM;       // 62 MB .. 64 MB

    CvtArgs ca;
    ca.src[0] = query; ca.dst[0] = qbf;  ca.n4[0] = (int)(NELEM / 4);
    ca.src[1] = key;   ca.dst[1] = kbf;  ca.n4[1] = (int)(NELEM / 4);
    ca.src[2] = value; ca.dst[2] = vbf;  ca.n4[2] = (int)(NELEM / 4);
    ca.src[3] = q_w;   ca.dst[3] = qwbf; ca.n4[3] = (int)(WELEM / 4);
    ca.src[4] = k_w;   ca.dst[4] = kwbf; ca.n4[4] = (int)(WELEM / 4);
    ca.src[5] = v_w;   ca.dst[5] = vwbf; ca.n4[5] = (int)(WELEM / 4);
    ca.src[6] = o_w;   ca.dst[6] = owbf; ca.n4[6] = (int)(WELEM / 4);
    cvt_kernel<<<dim3(256, 7), blk, 0, stream>>>(ca);

    qkv_gemm_kernel<<<dim3(8, 32, 3), blk, 0, stream>>>(
        qbf, kbf, vbf, qwbf, kwbf, vwbf, q_b, k_b, v_b, Qbuf, Kbuf, Vbuf, QSCALE);

    attn_kernel<<<dim3(32, 32), blk, 0, stream>>>(Qbuf, Kbuf, Vbuf, ctxb);

    o_gemm_kernel<<<dim3(16, 32), blk, 0, stream>>>(ctxb, owbf, o_b, (float*)d_out);
  } else {
    // ---- fallback: fp32-input reg-staged GEMMs
    const dim3 ggrid(8, 32);
    gemm_bt_kernel<false, 1><<<ggrid, blk, 0, stream>>>(query, q_w, q_b, Qbuf, QSCALE);
    gemm_bt_kernel<false, 1><<<ggrid, blk, 0, stream>>>(key, k_w, k_b, Kbuf, 1.0f);
    gemm_bt_kernel<false, 2><<<ggrid, blk, 0, stream>>>(value, v_w, v_b, Vbuf, 1.0f);
    attn_kernel<<<dim3(32, 32), blk, 0, stream>>>(Qbuf, Kbuf, Vbuf, ctxb);
    gemm_bt_kernel<true, 0><<<ggrid, blk, 0, stream>>>(ctxb, o_w, o_b, d_out, 1.0f);
  }
}